// Round 3
// baseline (239.640 us; speedup 1.0000x reference)
//
#include <hip/hip_runtime.h>
#include <hip/hip_bf16.h>

#define N_PTS 4096
#define C_LIGHT 0.49965409666666664f
#define BN_EPS 1e-3f

typedef __attribute__((ext_vector_type(8))) short short8;
typedef __attribute__((ext_vector_type(4))) float f32x4;

static __device__ __forceinline__ unsigned short f2bf(float f) {
    unsigned u = __float_as_uint(f);
    u += 0x7FFFu + ((u >> 16) & 1u);   // round-to-nearest-even
    return (unsigned short)(u >> 16);
}
static __device__ __forceinline__ float bf2f(unsigned short h) {
    return __uint_as_float(((unsigned)h) << 16);
}
// pack 2 floats -> 2 bf16 (RNE) in one u32 (lo = a, hi = b); maps to v_cvt_pk_bf16_f32
static __device__ __forceinline__ unsigned pk2(float a, float b) {
    __hip_bfloat162 h = __float22bfloat162_rn(make_float2(a, b));
    union { __hip_bfloat162 v; unsigned u; } cv;
    cv.v = h;
    return cv.u;
}

// ---------------------------------------------------------------------------
// Fold: per branch (blockIdx 0=m, 1=f):
//   s0,t0; Bf = b1 + t0@W1; S1,T1; Wf = diag(s0)@W1 split to bf16 hi/lo in
//   B-fragment order [ct(16)][ks(4)][lane(64)][j(8)]:
//   element = Wf[ks*32 + (lane>>4)*8 + j][ct*16 + (lane&15)]
// ---------------------------------------------------------------------------
__global__ __launch_bounds__(256) void fold_kernel(
    const float* __restrict__ mW1, const float* __restrict__ mb1,
    const float* __restrict__ mg0, const float* __restrict__ mbe0,
    const float* __restrict__ mmu0, const float* __restrict__ mvar0,
    const float* __restrict__ mg1, const float* __restrict__ mbe1,
    const float* __restrict__ mmu1, const float* __restrict__ mvar1,
    const float* __restrict__ fW1p, const float* __restrict__ fb1,
    const float* __restrict__ fg0, const float* __restrict__ fbe0,
    const float* __restrict__ fmu0, const float* __restrict__ fvar0,
    const float* __restrict__ fg1, const float* __restrict__ fbe1,
    const float* __restrict__ fmu1, const float* __restrict__ fvar1,
    float* __restrict__ mBf, float* __restrict__ mS1, float* __restrict__ mT1,
    unsigned short* __restrict__ mWhi, unsigned short* __restrict__ mWlo,
    float* __restrict__ fBf, float* __restrict__ fS1, float* __restrict__ fT1,
    unsigned short* __restrict__ fWhi, unsigned short* __restrict__ fWlo)
{
    int br = blockIdx.x;
    const float* W1  = br ? fW1p : mW1;
    const float* b1  = br ? fb1  : mb1;
    const float* g0  = br ? fg0  : mg0;
    const float* be0 = br ? fbe0 : mbe0;
    const float* mu0 = br ? fmu0 : mmu0;
    const float* var0= br ? fvar0: mvar0;
    const float* g1  = br ? fg1  : mg1;
    const float* be1 = br ? fbe1 : mbe1;
    const float* mu1 = br ? fmu1 : mmu1;
    const float* var1= br ? fvar1: mvar1;
    float* Bf = br ? fBf : mBf;
    float* S1 = br ? fS1 : mS1;
    float* T1 = br ? fT1 : mT1;
    unsigned short* Whi = br ? fWhi : mWhi;
    unsigned short* Wlo = br ? fWlo : mWlo;

    __shared__ float s0s[128], t0s[128];
    int t = threadIdx.x;
    if (t < 128) {
        float s = g0[t] / sqrtf(var0[t] + BN_EPS);
        s0s[t] = s;
        t0s[t] = be0[t] - mu0[t] * s;
    }
    __syncthreads();

    {
        float s1 = g1[t] / sqrtf(var1[t] + BN_EPS);
        S1[t] = s1;
        T1[t] = be1[t] - mu1[t] * s1;
        float acc = b1[t];
        for (int i = 0; i < 128; ++i) acc = fmaf(t0s[i], W1[i * 256 + t], acc);
        Bf[t] = acc;
    }

    for (int e = t; e < 32768; e += 256) {
        int j = e & 7, l = (e >> 3) & 63, ks = (e >> 9) & 3, ct = e >> 11;
        int i = ks * 32 + (l >> 4) * 8 + j;
        int c = ct * 16 + (l & 15);
        float w = s0s[i] * W1[i * 256 + c];
        unsigned short hi = f2bf(w);
        unsigned short lo = f2bf(w - bf2f(hi));
        Whi[e] = hi;
        Wlo[e] = lo;
    }
}

// ---------------------------------------------------------------------------
// FR branch (MFMA): 64 rows/block. Output stored TRANSPOSED:
//   frT[col][grow] (col-major), so stores here and loads in fused vectorize.
// ---------------------------------------------------------------------------
__global__ __launch_bounds__(256, 2) void fr_kernel(
    const float* __restrict__ x,    // (32768, 6)
    const float* __restrict__ W0,   // 6x128
    const float* __restrict__ b0,
    const short8* __restrict__ WfHi, const short8* __restrict__ WfLo,
    const float* __restrict__ Bf, const float* __restrict__ S1,
    const float* __restrict__ T1,
    float* __restrict__ frT)        // (256, 32768) col-major of fr
{
    __shared__ float xs[64][6];
    __shared__ __attribute__((aligned(16))) float w0s[6][136];
    __shared__ __attribute__((aligned(16))) float b0s[128];
    __shared__ __attribute__((aligned(16))) unsigned short hAhi[4 * 64 * 8];
    __shared__ __attribute__((aligned(16))) unsigned short hAlo[4 * 64 * 8];

    int t = threadIdx.x;
    long row0 = (long)blockIdx.x * 64;

    for (int i = t; i < 384; i += 256) xs[i / 6][i % 6] = x[row0 * 6 + i];
    for (int i = t; i < 768; i += 256) w0s[i >> 7][i & 127] = W0[i];
    if (t < 128) b0s[t] = b0[t];

    int lane = t & 63, wv = t >> 6;
    int laneN = lane & 15, laneH = lane >> 4;
    int cg = t & 7;

    float bfv[4], s1v[4], t1v[4];
    int colc[4];
#pragma unroll
    for (int c = 0; c < 4; ++c) {
        colc[c] = (wv * 4 + c) * 16 + laneN;
        bfv[c] = Bf[colc[c]];
        s1v[c] = S1[colc[c]];
        t1v[c] = T1[colc[c]];
    }
    f32x4 acc[4][4];
#pragma unroll
    for (int mt = 0; mt < 4; ++mt)
#pragma unroll
        for (int c = 0; c < 4; ++c) {
            f32x4 z = {bfv[c], bfv[c], bfv[c], bfv[c]};
            acc[mt][c] = z;
        }
    __syncthreads();

    for (int ks = 0; ks < 4; ++ks) {
        int k0 = ks * 32 + cg * 4;
        float4 wreg[6];
#pragma unroll
        for (int i = 0; i < 6; ++i) wreg[i] = *(const float4*)&w0s[i][k0];
        float4 bq = *(const float4*)&b0s[k0];

        for (int idx = t; idx < 512; idx += 256) {
            int row = idx >> 3;   // 0..63 ; (idx&7)==cg
            float a0 = bq.x, a1 = bq.y, a2 = bq.z, a3 = bq.w;
#pragma unroll
            for (int i = 0; i < 6; ++i) {
                float hv = xs[row][i];
                a0 = fmaf(hv, wreg[i].x, a0);
                a1 = fmaf(hv, wreg[i].y, a1);
                a2 = fmaf(hv, wreg[i].z, a2);
                a3 = fmaf(hv, wreg[i].w, a3);
            }
            a0 = fmaxf(a0, 0.f); a1 = fmaxf(a1, 0.f);
            a2 = fmaxf(a2, 0.f); a3 = fmaxf(a3, 0.f);
            unsigned hi01 = pk2(a0, a1), hi23 = pk2(a2, a3);
            float q0 = __uint_as_float(hi01 << 16);
            float q1 = __uint_as_float(hi01 & 0xffff0000u);
            float q2 = __uint_as_float(hi23 << 16);
            float q3 = __uint_as_float(hi23 & 0xffff0000u);
            unsigned lo01 = pk2(a0 - q0, a1 - q1), lo23 = pk2(a2 - q2, a3 - q3);
            int mt = row >> 4, nl = row & 15;
            int base = (mt * 64 + (cg >> 1) * 16 + nl) * 8 + (cg & 1) * 4;
            *(uint2*)&hAhi[base] = make_uint2(hi01, hi23);
            *(uint2*)&hAlo[base] = make_uint2(lo01, lo23);
        }
        __syncthreads();

        short8 Bhi[4], Blo[4];
#pragma unroll
        for (int c = 0; c < 4; ++c) {
            int fo = ((wv * 4 + c) * 4 + ks) * 64 + lane;
            Bhi[c] = WfHi[fo];
            Blo[c] = WfLo[fo];
        }
#pragma unroll
        for (int mt = 0; mt < 4; ++mt) {
            short8 Ahi = *(const short8*)&hAhi[(mt * 64 + lane) * 8];
            short8 Alo = *(const short8*)&hAlo[(mt * 64 + lane) * 8];
#pragma unroll
            for (int c = 0; c < 4; ++c) {
                f32x4 a = acc[mt][c];
                a = __builtin_amdgcn_mfma_f32_16x16x32_bf16(Alo, Bhi[c], a, 0, 0, 0);
                a = __builtin_amdgcn_mfma_f32_16x16x32_bf16(Ahi, Blo[c], a, 0, 0, 0);
                a = __builtin_amdgcn_mfma_f32_16x16x32_bf16(Ahi, Bhi[c], a, 0, 0, 0);
                acc[mt][c] = a;
            }
        }
        __syncthreads();
    }

    // store transposed: frT[col][row0 + mt*16 + laneH*4 .. +3] as float4
#pragma unroll
    for (int c = 0; c < 4; ++c)
#pragma unroll
        for (int mt = 0; mt < 4; ++mt) {
            float4 o;
            o.x = fmaf(fmaxf(acc[mt][c][0], 0.f), s1v[c], t1v[c]);
            o.y = fmaf(fmaxf(acc[mt][c][1], 0.f), s1v[c], t1v[c]);
            o.z = fmaf(fmaxf(acc[mt][c][2], 0.f), s1v[c], t1v[c]);
            o.w = fmaf(fmaxf(acc[mt][c][3], 0.f), s1v[c], t1v[c]);
            *(float4*)&frT[(long)colc[c] * 32768 + row0 + mt * 16 + laneH * 4] = o;
        }
}

// ---------------------------------------------------------------------------
// Fused H + M-branch + A-layer (MFMA).
// 256 thr, 16 n/block, 144 rows = 9 M-tiles (tile index == k);
// max over k = register max over the 9 accumulator tiles, gated by frT
// staged in LDS. LDS is phase-unioned (A-frag buffers die before frT stage).
// ---------------------------------------------------------------------------
#define SM_XS   0        // 24*6  f32 = 576
#define SM_B0   576      // 128   f32 = 512
#define SM_W0   1088     // 12*136 f32 = 6528
#define SM_HF   7616     // 144*12 f32 = 6912
#define SM_AHI  14528    // 4608 u16 = 9216
#define SM_ALO  23744    // 4608 u16 = 9216  (ends 32960)
#define SM_FRT  0        // 256*33 f32 = 33792 (phase B, overlays phase A)
#define SM_OUT  33792    // 16*260 f32 = 16640
#define SM_TOT  50432

__global__ __launch_bounds__(256, 2) void fused_kernel(
    const float* __restrict__ x,    // (B, N, 6)
    const float* __restrict__ W0,   // 12x128
    const float* __restrict__ b0,
    const short8* __restrict__ WfHi, const short8* __restrict__ WfLo,
    const float* __restrict__ Bf, const float* __restrict__ S1,
    const float* __restrict__ T1,
    const float* __restrict__ frT,  // (256, 32768) col-major
    float* __restrict__ out)        // (B, N, 256)
{
    __shared__ __attribute__((aligned(16))) char smem[SM_TOT];
    float* xs  = (float*)(smem + SM_XS);
    float* b0s = (float*)(smem + SM_B0);
    float* w0s = (float*)(smem + SM_W0);
    float* hfp = (float*)(smem + SM_HF);
    unsigned short* hAhi = (unsigned short*)(smem + SM_AHI);
    unsigned short* hAlo = (unsigned short*)(smem + SM_ALO);
    float* frL = (float*)(smem + SM_FRT);
    float* oL  = (float*)(smem + SM_OUT);

    int t = threadIdx.x;
    int bn = blockIdx.x;
    int b  = bn >> 8;               // 256 blocks per batch
    int n0 = (bn & 255) << 4;
    const float* xb = x + (long)b * N_PTS * 6;

    if (t < 144) {                  // 24 rows x 6 cols
        int rr = t / 6, cc = t % 6;
        int n = n0 - 4 + rr;
        xs[rr * 6 + cc] = (n >= 0 && n < N_PTS) ? xb[n * 6 + cc] : 0.f;
    }
    for (int i = t; i < 12 * 128; i += 256) w0s[(i >> 7) * 136 + (i & 127)] = W0[i];
    if (t < 128) b0s[t] = b0[t];
    __syncthreads();

    if (t < 144) {                  // row = kt*16 + nl
        int kt = t >> 4, nl = t & 15;
        const float* self = &xs[(nl + 4) * 6];
        const float* nb   = &xs[(nl + kt) * 6];
        int nbn = n0 + nl + kt - 4;
        float msk = (nbn >= 0 && nbn < N_PTS) ? 1.f : 0.f;
        float dt = (nb[0] - self[0]) * msk;
        float dx = (nb[3] - self[3]) * msk;
        float dy = (nb[4] - self[4]) * msk;
        float dz = (nb[5] - self[5]) * msk;
        float eu2 = dx * dx + dy * dy + dz * dz;
        float* h = &hfp[t * 12];
        h[0]  = nb[0];
        h[1]  = nb[3];
        h[2]  = nb[4];
        h[3]  = nb[5];
        h[4]  = nb[1];
        h[5]  = nb[2];
        h[6]  = dt;
        h[7]  = dx;
        h[8]  = dy;
        h[9]  = dz;
        h[10] = sqrtf(eu2);
        float cdt = C_LIGHT * dt;
        h[11] = cdt * cdt - eu2;
    }

    int lane = t & 63, wv = t >> 6;
    int laneN = lane & 15, laneH = lane >> 4;
    int cg = t & 7;

    float bfv[4], s1v[4], t1v[4];
    int colc[4];
#pragma unroll
    for (int c = 0; c < 4; ++c) {
        colc[c] = (wv * 4 + c) * 16 + laneN;
        bfv[c] = Bf[colc[c]];
        s1v[c] = S1[colc[c]];
        t1v[c] = T1[colc[c]];
    }
    f32x4 acc[9][4];
#pragma unroll
    for (int kt = 0; kt < 9; ++kt)
#pragma unroll
        for (int c = 0; c < 4; ++c) {
            f32x4 z = {bfv[c], bfv[c], bfv[c], bfv[c]};
            acc[kt][c] = z;
        }
    __syncthreads();

    for (int ks = 0; ks < 4; ++ks) {
        int k0 = ks * 32 + cg * 4;
        float4 wreg[12];
#pragma unroll
        for (int i = 0; i < 12; ++i) wreg[i] = *(const float4*)&w0s[i * 136 + k0];
        float4 bq = *(const float4*)&b0s[k0];

        for (int idx = t; idx < 1152; idx += 256) {
            int row = idx >> 3;     // 0..143 ; (idx&7)==cg
            float a0 = bq.x, a1 = bq.y, a2 = bq.z, a3 = bq.w;
#pragma unroll
            for (int i = 0; i < 12; ++i) {
                float hv = hfp[row * 12 + i];
                a0 = fmaf(hv, wreg[i].x, a0);
                a1 = fmaf(hv, wreg[i].y, a1);
                a2 = fmaf(hv, wreg[i].z, a2);
                a3 = fmaf(hv, wreg[i].w, a3);
            }
            a0 = fmaxf(a0, 0.f); a1 = fmaxf(a1, 0.f);
            a2 = fmaxf(a2, 0.f); a3 = fmaxf(a3, 0.f);
            unsigned hi01 = pk2(a0, a1), hi23 = pk2(a2, a3);
            float q0 = __uint_as_float(hi01 << 16);
            float q1 = __uint_as_float(hi01 & 0xffff0000u);
            float q2 = __uint_as_float(hi23 << 16);
            float q3 = __uint_as_float(hi23 & 0xffff0000u);
            unsigned lo01 = pk2(a0 - q0, a1 - q1), lo23 = pk2(a2 - q2, a3 - q3);
            int kt = row >> 4, nl = row & 15;
            int base = (kt * 64 + (cg >> 1) * 16 + nl) * 8 + (cg & 1) * 4;
            *(uint2*)&hAhi[base] = make_uint2(hi01, hi23);
            *(uint2*)&hAlo[base] = make_uint2(lo01, lo23);
        }
        __syncthreads();

        short8 Bhi[4], Blo[4];
#pragma unroll
        for (int c = 0; c < 4; ++c) {
            int fo = ((wv * 4 + c) * 4 + ks) * 64 + lane;
            Bhi[c] = WfHi[fo];
            Blo[c] = WfLo[fo];
        }
#pragma unroll
        for (int kt = 0; kt < 9; ++kt) {
            short8 Ahi = *(const short8*)&hAhi[(kt * 64 + lane) * 8];
            short8 Alo = *(const short8*)&hAlo[(kt * 64 + lane) * 8];
#pragma unroll
            for (int c = 0; c < 4; ++c) {
                f32x4 a = acc[kt][c];
                a = __builtin_amdgcn_mfma_f32_16x16x32_bf16(Alo, Bhi[c], a, 0, 0, 0);
                a = __builtin_amdgcn_mfma_f32_16x16x32_bf16(Ahi, Blo[c], a, 0, 0, 0);
                a = __builtin_amdgcn_mfma_f32_16x16x32_bf16(Ahi, Bhi[c], a, 0, 0, 0);
                acc[kt][c] = a;
            }
        }
        __syncthreads();
    }
    // phase A LDS now dead; stage frT window [n0-8, n0+23] into LDS (phase B)
    for (int i = t; i < 2048; i += 256) {
        int col = i >> 3, seg = i & 7;
        int nn = n0 - 8 + seg * 4;
        float4 v = make_float4(0.f, 0.f, 0.f, 0.f);
        if (nn >= 0 && nn < N_PTS)
            v = *(const float4*)&frT[(long)col * 32768 + (b << 12) + nn];
        *(float4*)&frL[col * 33 + seg * 4] = v;
    }
    __syncthreads();

    // Epilogue: m = relu(acc)*S1+T1; T = m * fr[n+kt-4]; out = max_kt T
#pragma unroll
    for (int c = 0; c < 4; ++c) {
        float fv[12];
        int fb = colc[c] * 33 + laneH * 4 + 4;   // lds row = nl + kt + 4
#pragma unroll
        for (int j = 0; j < 12; ++j) fv[j] = frL[fb + j];
#pragma unroll
        for (int r = 0; r < 4; ++r) {
            float best;
#pragma unroll
            for (int kt = 0; kt < 9; ++kt) {
                float m = fmaf(fmaxf(acc[kt][c][r], 0.f), s1v[c], t1v[c]);
                float T = m * fv[r + kt];
                best = (kt == 0) ? T : fmaxf(best, T);
            }
            oL[(laneH * 4 + r) * 260 + colc[c]] = best;
        }
    }
    __syncthreads();

    float* outb = out + ((long)b << 20);
    for (int i = t; i < 1024; i += 256) {
        int row = i >> 6, c4 = (i & 63) << 2;
        float4 v = *(const float4*)&oL[row * 260 + c4];
        *(float4*)&outb[((long)(n0 + row) << 8) + c4] = v;
    }
}

// ---------------------------------------------------------------------------
extern "C" void kernel_launch(void* const* d_in, const int* in_sizes, int n_in,
                              void* d_out, int out_size, void* d_ws, size_t ws_size,
                              hipStream_t stream)
{
    const float* x = (const float*)d_in[0];
    const float* m_W0  = (const float*)d_in[1];
    const float* f_W0  = (const float*)d_in[2];
    const float* m_b0  = (const float*)d_in[3];
    const float* f_b0  = (const float*)d_in[4];
    const float* m_g0  = (const float*)d_in[5];
    const float* f_g0  = (const float*)d_in[6];
    const float* m_be0 = (const float*)d_in[7];
    const float* f_be0 = (const float*)d_in[8];
    const float* m_mu0 = (const float*)d_in[9];
    const float* f_mu0 = (const float*)d_in[10];
    const float* m_var0= (const float*)d_in[11];
    const float* f_var0= (const float*)d_in[12];
    const float* m_W1  = (const float*)d_in[13];
    const float* f_W1  = (const float*)d_in[14];
    const float* m_b1  = (const float*)d_in[15];
    const float* f_b1  = (const float*)d_in[16];
    const float* m_g1  = (const float*)d_in[17];
    const float* f_g1  = (const float*)d_in[18];
    const float* m_be1 = (const float*)d_in[19];
    const float* f_be1 = (const float*)d_in[20];
    const float* m_mu1 = (const float*)d_in[21];
    const float* f_mu1 = (const float*)d_in[22];
    const float* m_var1= (const float*)d_in[23];
    const float* f_var1= (const float*)d_in[24];

    char* wsb = (char*)d_ws;
    float* frT = (float*)wsb;                       // 256 x 32768 f32 = 33,554,432 B
    float* mBf = (float*)(wsb + 33554432);
    float* mS1 = mBf + 256;
    float* mT1 = mS1 + 256;
    float* fBf = mT1 + 256;
    float* fS1 = fBf + 256;
    float* fT1 = fS1 + 256;
    unsigned short* mWhi = (unsigned short*)(fT1 + 256);  // 32768 each
    unsigned short* mWlo = mWhi + 32768;
    unsigned short* fWhi = mWlo + 32768;
    unsigned short* fWlo = fWhi + 32768;

    fold_kernel<<<2, 256, 0, stream>>>(
        m_W1, m_b1, m_g0, m_be0, m_mu0, m_var0, m_g1, m_be1, m_mu1, m_var1,
        f_W1, f_b1, f_g0, f_be0, f_mu0, f_var0, f_g1, f_be1, f_mu1, f_var1,
        mBf, mS1, mT1, mWhi, mWlo,
        fBf, fS1, fT1, fWhi, fWlo);

    fr_kernel<<<8 * N_PTS / 64, 256, 0, stream>>>(
        x, f_W0, f_b0, (const short8*)fWhi, (const short8*)fWlo,
        fBf, fS1, fT1, frT);

    fused_kernel<<<8 * N_PTS / 16, 256, 0, stream>>>(
        x, m_W0, m_b0, (const short8*)mWhi, (const short8*)mWlo,
        mBf, mS1, mT1, frT, (float*)d_out);
}

// Round 7
// 204.566 us; speedup vs baseline: 1.1715x; 1.1715x over previous
//
#include <hip/hip_runtime.h>
#include <hip/hip_bf16.h>

#define N_PTS 4096
#define C_LIGHT 0.49965409666666664f
#define BN_EPS 1e-3f

typedef __attribute__((ext_vector_type(8))) short short8;
typedef __attribute__((ext_vector_type(4))) float f32x4;

static __device__ __forceinline__ unsigned short f2bf(float f) {
    unsigned u = __float_as_uint(f);
    u += 0x7FFFu + ((u >> 16) & 1u);
    return (unsigned short)(u >> 16);
}
static __device__ __forceinline__ float bf2f(unsigned short h) {
    return __uint_as_float(((unsigned)h) << 16);
}
// pack 2 floats -> 2 bf16 (RNE) in one u32; maps to v_cvt_pk_bf16_f32
static __device__ __forceinline__ unsigned pk2(float a, float b) {
    __hip_bfloat162 h = __float22bfloat162_rn(make_float2(a, b));
    union { __hip_bfloat162 v; unsigned u; } cv;
    cv.v = h;
    return cv.u;
}

// ---------------------------------------------------------------------------
// fold_bias: per branch (blockIdx 0=m, 1=f): Bf = b1 + t0@W1; S1; T1.
// ---------------------------------------------------------------------------
__global__ __launch_bounds__(256) void fold_bias(
    const float* __restrict__ mW1, const float* __restrict__ mb1,
    const float* __restrict__ mg0, const float* __restrict__ mbe0,
    const float* __restrict__ mmu0, const float* __restrict__ mvar0,
    const float* __restrict__ mg1, const float* __restrict__ mbe1,
    const float* __restrict__ mmu1, const float* __restrict__ mvar1,
    const float* __restrict__ fW1p, const float* __restrict__ fb1,
    const float* __restrict__ fg0, const float* __restrict__ fbe0,
    const float* __restrict__ fmu0, const float* __restrict__ fvar0,
    const float* __restrict__ fg1, const float* __restrict__ fbe1,
    const float* __restrict__ fmu1, const float* __restrict__ fvar1,
    float* __restrict__ mBf, float* __restrict__ mS1, float* __restrict__ mT1,
    float* __restrict__ fBf, float* __restrict__ fS1, float* __restrict__ fT1)
{
    int br = blockIdx.x;
    const float* W1  = br ? fW1p : mW1;
    const float* b1  = br ? fb1  : mb1;
    const float* g0  = br ? fg0  : mg0;
    const float* be0 = br ? fbe0 : mbe0;
    const float* mu0 = br ? fmu0 : mmu0;
    const float* var0= br ? fvar0: mvar0;
    const float* g1  = br ? fg1  : mg1;
    const float* be1 = br ? fbe1 : mbe1;
    const float* mu1 = br ? fmu1 : mmu1;
    const float* var1= br ? fvar1: mvar1;
    float* Bf = br ? fBf : mBf;
    float* S1 = br ? fS1 : mS1;
    float* T1 = br ? fT1 : mT1;

    __shared__ float t0s[128];
    int t = threadIdx.x;
    if (t < 128) {
        float s = g0[t] / sqrtf(var0[t] + BN_EPS);
        t0s[t] = be0[t] - mu0[t] * s;
    }
    __syncthreads();

    float s1 = g1[t] / sqrtf(var1[t] + BN_EPS);
    S1[t] = s1;
    T1[t] = be1[t] - mu1[t] * s1;
    float acc = b1[t];
    for (int i = 0; i < 128; ++i) acc = fmaf(t0s[i], W1[i * 256 + t], acc);
    Bf[t] = acc;
}

// ---------------------------------------------------------------------------
// fold_w: 32 blocks (16 per branch). Wf = diag(s0)@W1 split to bf16 hi/lo in
// B-fragment order [ct(16)][ks(4)][lane(64)][j(8)]:
//   element = Wf[ks*32 + (lane>>4)*8 + j][ct*16 + (lane&15)]
// Thread handles 8 consecutive e (one (l,ks,ct), j=0..7) -> 16B uint4 stores.
// ---------------------------------------------------------------------------
__global__ __launch_bounds__(256) void fold_w(
    const float* __restrict__ mW1,
    const float* __restrict__ mg0, const float* __restrict__ mvar0,
    const float* __restrict__ fW1p,
    const float* __restrict__ fg0, const float* __restrict__ fvar0,
    unsigned short* __restrict__ mWhi, unsigned short* __restrict__ mWlo,
    unsigned short* __restrict__ fWhi, unsigned short* __restrict__ fWlo)
{
    int bid = blockIdx.x;
    int br = bid >> 4, blk = bid & 15;
    const float* W1  = br ? fW1p : mW1;
    const float* g0  = br ? fg0  : mg0;
    const float* var0= br ? fvar0: mvar0;
    unsigned short* Whi = br ? fWhi : mWhi;
    unsigned short* Wlo = br ? fWlo : mWlo;

    __shared__ float s0s[128];
    int t = threadIdx.x;
    if (t < 128) s0s[t] = g0[t] / sqrtf(var0[t] + BN_EPS);
    __syncthreads();

    int e0 = blk * 2048 + t * 8;
    int l = (e0 >> 3) & 63, ks = (e0 >> 9) & 3, ct = e0 >> 11;
    int c = ct * 16 + (l & 15);
    int ib = ks * 32 + (l >> 4) * 8;
    unsigned short hi[8], lo[8];
#pragma unroll
    for (int j = 0; j < 8; ++j) {
        float w = s0s[ib + j] * W1[(ib + j) * 256 + c];
        hi[j] = f2bf(w);
        lo[j] = f2bf(w - bf2f(hi[j]));
    }
    *(uint4*)&Whi[e0] = *(uint4*)hi;
    *(uint4*)&Wlo[e0] = *(uint4*)lo;
}

// ---------------------------------------------------------------------------
// FR branch (MFMA): 32 rows/block, 1024 blocks. Double-buffered A-frags,
// one barrier per ks. Row-major output via LDS-staged coalesced stores.
// ---------------------------------------------------------------------------
__global__ __launch_bounds__(256, 3) void fr_kernel(
    const float* __restrict__ x,    // (32768, 6)
    const float* __restrict__ W0,   // 6x128
    const float* __restrict__ b0,
    const short8* __restrict__ WfHi, const short8* __restrict__ WfLo,
    const float* __restrict__ Bf, const float* __restrict__ S1,
    const float* __restrict__ T1,
    float* __restrict__ fr)         // (32768, 256) row-major
{
    __shared__ float xs[32][6];
    __shared__ __attribute__((aligned(16))) float w0s[6][136];
    __shared__ __attribute__((aligned(16))) float b0s[128];
    __shared__ __attribute__((aligned(16))) unsigned short hAhi[2][1024];
    __shared__ __attribute__((aligned(16))) unsigned short hAlo[2][1024];
    __shared__ __attribute__((aligned(16))) float oL[32][260];

    int t = threadIdx.x;
    long row0 = (long)blockIdx.x * 32;

    if (t < 192) xs[t / 6][t % 6] = x[row0 * 6 + t];
    for (int i = t; i < 768; i += 256) w0s[i >> 7][i & 127] = W0[i];
    if (t < 128) b0s[t] = b0[t];

    int lane = t & 63, wv = t >> 6;
    int laneN = lane & 15, laneH = lane >> 4;
    int cg = t & 7;
    int rowh = t >> 3;              // 0..31: hidden row this thread owns

    float bfv[4], s1v[4], t1v[4];
    int colc[4];
#pragma unroll
    for (int c = 0; c < 4; ++c) {
        colc[c] = (wv * 4 + c) * 16 + laneN;
        bfv[c] = Bf[colc[c]];
        s1v[c] = S1[colc[c]];
        t1v[c] = T1[colc[c]];
    }
    f32x4 acc[2][4];
#pragma unroll
    for (int mt = 0; mt < 2; ++mt)
#pragma unroll
        for (int c = 0; c < 4; ++c) {
            f32x4 z = {bfv[c], bfv[c], bfv[c], bfv[c]};
            acc[mt][c] = z;
        }
    __syncthreads();

    // hidden slice for one ks into buffer bi (1 row-group per thread)
#define FR_HIDDEN(ks, bi)                                                     \
    {                                                                         \
        int k0 = (ks) * 32 + cg * 4;                                          \
        float a0 = b0s[k0], a1 = b0s[k0+1], a2 = b0s[k0+2], a3 = b0s[k0+3];   \
        _Pragma("unroll")                                                     \
        for (int i = 0; i < 6; ++i) {                                         \
            float hv = xs[rowh][i];                                           \
            a0 = fmaf(hv, w0s[i][k0],   a0);                                  \
            a1 = fmaf(hv, w0s[i][k0+1], a1);                                  \
            a2 = fmaf(hv, w0s[i][k0+2], a2);                                  \
            a3 = fmaf(hv, w0s[i][k0+3], a3);                                  \
        }                                                                     \
        a0 = fmaxf(a0, 0.f); a1 = fmaxf(a1, 0.f);                             \
        a2 = fmaxf(a2, 0.f); a3 = fmaxf(a3, 0.f);                             \
        unsigned hi01 = pk2(a0, a1), hi23 = pk2(a2, a3);                      \
        float q0 = __uint_as_float(hi01 << 16);                               \
        float q1 = __uint_as_float(hi01 & 0xffff0000u);                       \
        float q2 = __uint_as_float(hi23 << 16);                               \
        float q3 = __uint_as_float(hi23 & 0xffff0000u);                       \
        unsigned lo01 = pk2(a0 - q0, a1 - q1), lo23 = pk2(a2 - q2, a3 - q3);  \
        int mt = rowh >> 4, nl = rowh & 15;                                   \
        int base = (mt * 64 + (cg >> 1) * 16 + nl) * 8 + (cg & 1) * 4;        \
        *(uint2*)&hAhi[bi][base] = make_uint2(hi01, hi23);                    \
        *(uint2*)&hAlo[bi][base] = make_uint2(lo01, lo23);                    \
    }

    FR_HIDDEN(0, 0)
    __syncthreads();

    for (int ks = 0; ks < 4; ++ks) {
        int bi = ks & 1;
        short8 Bhi[4], Blo[4];
#pragma unroll
        for (int c = 0; c < 4; ++c) {
            int fo = ((wv * 4 + c) * 4 + ks) * 64 + lane;
            Bhi[c] = WfHi[fo];
            Blo[c] = WfLo[fo];
        }
#pragma unroll
        for (int mt = 0; mt < 2; ++mt) {
            short8 Ahi = *(const short8*)&hAhi[bi][(mt * 64 + lane) * 8];
            short8 Alo = *(const short8*)&hAlo[bi][(mt * 64 + lane) * 8];
#pragma unroll
            for (int c = 0; c < 4; ++c) {
                f32x4 a = acc[mt][c];
                a = __builtin_amdgcn_mfma_f32_16x16x32_bf16(Alo, Bhi[c], a, 0, 0, 0);
                a = __builtin_amdgcn_mfma_f32_16x16x32_bf16(Ahi, Blo[c], a, 0, 0, 0);
                a = __builtin_amdgcn_mfma_f32_16x16x32_bf16(Ahi, Bhi[c], a, 0, 0, 0);
                acc[mt][c] = a;
            }
        }
        if (ks < 3) FR_HIDDEN(ks + 1, bi ^ 1)
        __syncthreads();
    }

#pragma unroll
    for (int c = 0; c < 4; ++c)
#pragma unroll
        for (int mt = 0; mt < 2; ++mt)
#pragma unroll
            for (int r = 0; r < 4; ++r)
                oL[mt * 16 + laneH * 4 + r][colc[c]] =
                    fmaf(fmaxf(acc[mt][c][r], 0.f), s1v[c], t1v[c]);
    __syncthreads();

    for (int i = t; i < 2048; i += 256) {
        int row = i >> 6, c4 = (i & 63) << 2;
        float4 v = *(const float4*)&oL[row][c4];
        *(float4*)&fr[(row0 + row) * 256 + c4] = v;
    }
}

// ---------------------------------------------------------------------------
// Fused H + M-branch + A-layer (MFMA), double-buffered A-frags,
// one barrier per ks; epilogue stages row-major fr window in dead frag LDS.
// ---------------------------------------------------------------------------
#define SM_XS   0        // 24*6*4   = 576
#define SM_B0   576      // 512
#define SM_W0   1088     // 12*136*4 = 6528  -> 7616
#define SM_HF   7616     // 144*12*4 = 6912  -> 14528
#define SM_FRAG 14528    // 2 bufs * (hi 9216 + lo 9216) = 36864 -> 51392
#define SM_FRL  14528    // overlay: 24*260*4 = 24960
#define SM_OUT  51392    // 16*260*4 = 16640 -> 68032
#define SM_TOT  68032

__global__ __launch_bounds__(256, 2) void fused_kernel(
    const float* __restrict__ x,    // (B, N, 6)
    const float* __restrict__ W0,   // 12x128
    const float* __restrict__ b0,
    const short8* __restrict__ WfHi, const short8* __restrict__ WfLo,
    const float* __restrict__ Bf, const float* __restrict__ S1,
    const float* __restrict__ T1,
    const float* __restrict__ fr,   // (B*N, 256) row-major
    float* __restrict__ out)        // (B, N, 256)
{
    __shared__ __attribute__((aligned(16))) char smem[SM_TOT];
    float* xs  = (float*)(smem + SM_XS);
    float* b0s = (float*)(smem + SM_B0);
    float* w0s = (float*)(smem + SM_W0);
    float* hfp = (float*)(smem + SM_HF);
    float* frL = (float*)(smem + SM_FRL);
    float* oL  = (float*)(smem + SM_OUT);

    int t = threadIdx.x;
    int bn = blockIdx.x;
    int b  = bn >> 8;
    int n0 = (bn & 255) << 4;
    const float* xb = x + (long)b * N_PTS * 6;

    if (t < 144) {
        int rr = t / 6, cc = t % 6;
        int n = n0 - 4 + rr;
        xs[rr * 6 + cc] = (n >= 0 && n < N_PTS) ? xb[n * 6 + cc] : 0.f;
    }
    for (int i = t; i < 12 * 128; i += 256) w0s[(i >> 7) * 136 + (i & 127)] = W0[i];
    if (t < 128) b0s[t] = b0[t];
    __syncthreads();

    if (t < 144) {                  // row = kt*16 + nl
        int kt = t >> 4, nl = t & 15;
        const float* self = &xs[(nl + 4) * 6];
        const float* nb   = &xs[(nl + kt) * 6];
        int nbn = n0 + nl + kt - 4;
        float msk = (nbn >= 0 && nbn < N_PTS) ? 1.f : 0.f;
        float dt = (nb[0] - self[0]) * msk;
        float dx = (nb[3] - self[3]) * msk;
        float dy = (nb[4] - self[4]) * msk;
        float dz = (nb[5] - self[5]) * msk;
        float eu2 = dx * dx + dy * dy + dz * dz;
        float* h = &hfp[t * 12];
        h[0]  = nb[0];
        h[1]  = nb[3];
        h[2]  = nb[4];
        h[3]  = nb[5];
        h[4]  = nb[1];
        h[5]  = nb[2];
        h[6]  = dt;
        h[7]  = dx;
        h[8]  = dy;
        h[9]  = dz;
        h[10] = sqrtf(eu2);
        float cdt = C_LIGHT * dt;
        h[11] = cdt * cdt - eu2;
    }

    int lane = t & 63, wv = t >> 6;
    int laneN = lane & 15, laneH = lane >> 4;
    int cg = t & 7;

    float bfv[4], s1v[4], t1v[4];
    int colc[4];
#pragma unroll
    for (int c = 0; c < 4; ++c) {
        colc[c] = (wv * 4 + c) * 16 + laneN;
        bfv[c] = Bf[colc[c]];
        s1v[c] = S1[colc[c]];
        t1v[c] = T1[colc[c]];
    }
    f32x4 acc[9][4];
#pragma unroll
    for (int kt = 0; kt < 9; ++kt)
#pragma unroll
        for (int c = 0; c < 4; ++c) {
            f32x4 z = {bfv[c], bfv[c], bfv[c], bfv[c]};
            acc[kt][c] = z;
        }
    __syncthreads();

    // hidden slice for one ks -> frag buffer bi (4.5 row-groups per thread)
#define FU_HIDDEN(ks, bi)                                                     \
    {                                                                         \
        unsigned short* Hhi = (unsigned short*)(smem + SM_FRAG) + (bi) * 9216;\
        unsigned short* Hlo = Hhi + 4608;                                     \
        int k0 = (ks) * 32 + cg * 4;                                          \
        float4 wreg[12];                                                      \
        _Pragma("unroll")                                                     \
        for (int i = 0; i < 12; ++i) wreg[i] = *(const float4*)&w0s[i * 136 + k0]; \
        float4 bq = *(const float4*)&b0s[k0];                                 \
        for (int idx = t; idx < 1152; idx += 256) {                           \
            int row = idx >> 3;                                               \
            float a0 = bq.x, a1 = bq.y, a2 = bq.z, a3 = bq.w;                 \
            _Pragma("unroll")                                                 \
            for (int i = 0; i < 12; ++i) {                                    \
                float hv = hfp[row * 12 + i];                                 \
                a0 = fmaf(hv, wreg[i].x, a0);                                 \
                a1 = fmaf(hv, wreg[i].y, a1);                                 \
                a2 = fmaf(hv, wreg[i].z, a2);                                 \
                a3 = fmaf(hv, wreg[i].w, a3);                                 \
            }                                                                 \
            a0 = fmaxf(a0, 0.f); a1 = fmaxf(a1, 0.f);                         \
            a2 = fmaxf(a2, 0.f); a3 = fmaxf(a3, 0.f);                         \
            unsigned hi01 = pk2(a0, a1), hi23 = pk2(a2, a3);                  \
            float q0 = __uint_as_float(hi01 << 16);                           \
            float q1 = __uint_as_float(hi01 & 0xffff0000u);                   \
            float q2 = __uint_as_float(hi23 << 16);                           \
            float q3 = __uint_as_float(hi23 & 0xffff0000u);                   \
            unsigned lo01 = pk2(a0 - q0, a1 - q1), lo23 = pk2(a2 - q2, a3 - q3); \
            int kt = row >> 4, nl = row & 15;                                 \
            int base = (kt * 64 + (cg >> 1) * 16 + nl) * 8 + (cg & 1) * 4;    \
            *(uint2*)&Hhi[base] = make_uint2(hi01, hi23);                     \
            *(uint2*)&Hlo[base] = make_uint2(lo01, lo23);                     \
        }                                                                     \
    }

    FU_HIDDEN(0, 0)
    __syncthreads();

    for (int ks = 0; ks < 4; ++ks) {
        int bi = ks & 1;
        const unsigned short* Hhi = (const unsigned short*)(smem + SM_FRAG) + bi * 9216;
        const unsigned short* Hlo = Hhi + 4608;
        short8 Bhi[4], Blo[4];
#pragma unroll
        for (int c = 0; c < 4; ++c) {
            int fo = ((wv * 4 + c) * 4 + ks) * 64 + lane;
            Bhi[c] = WfHi[fo];
            Blo[c] = WfLo[fo];
        }
#pragma unroll
        for (int kt = 0; kt < 9; ++kt) {
            short8 Ahi = *(const short8*)&Hhi[(kt * 64 + lane) * 8];
            short8 Alo = *(const short8*)&Hlo[(kt * 64 + lane) * 8];
#pragma unroll
            for (int c = 0; c < 4; ++c) {
                f32x4 a = acc[kt][c];
                a = __builtin_amdgcn_mfma_f32_16x16x32_bf16(Alo, Bhi[c], a, 0, 0, 0);
                a = __builtin_amdgcn_mfma_f32_16x16x32_bf16(Ahi, Blo[c], a, 0, 0, 0);
                a = __builtin_amdgcn_mfma_f32_16x16x32_bf16(Ahi, Bhi[c], a, 0, 0, 0);
                acc[kt][c] = a;
            }
        }
        if (ks < 3) FU_HIDDEN(ks + 1, bi ^ 1)
        __syncthreads();
    }

    // frag LDS dead; stage fr rows [n0-4, n0+19] row-major (24 x 256)
    for (int i = t; i < 1536; i += 256) {
        int row = i >> 6, c4 = (i & 63) << 2;
        int nn = n0 - 4 + row;
        float4 v = make_float4(0.f, 0.f, 0.f, 0.f);
        if (nn >= 0 && nn < N_PTS)
            v = *(const float4*)&fr[(((long)(b << 12) + nn) << 8) + c4];
        *(float4*)&frL[row * 260 + c4] = v;
    }
    __syncthreads();

    // Epilogue: m = relu(acc)*S1+T1; T = m * fr[n+kt-4]; out = max_kt T
#pragma unroll
    for (int c = 0; c < 4; ++c) {
        float fv[12];
        int fb = (laneH * 4) * 260 + colc[c];   // relative row = nl + kt
#pragma unroll
        for (int j = 0; j < 12; ++j) fv[j] = frL[fb + j * 260];
#pragma unroll
        for (int r = 0; r < 4; ++r) {
            float best;
#pragma unroll
            for (int kt = 0; kt < 9; ++kt) {
                float m = fmaf(fmaxf(acc[kt][c][r], 0.f), s1v[c], t1v[c]);
                float T = m * fv[r + kt];
                best = (kt == 0) ? T : fmaxf(best, T);
            }
            oL[(laneH * 4 + r) * 260 + colc[c]] = best;
        }
    }
    __syncthreads();

    float* outb = out + ((long)b << 20);
    for (int i = t; i < 1024; i += 256) {
        int row = i >> 6, c4 = (i & 63) << 2;
        float4 v = *(const float4*)&oL[row * 260 + c4];
        *(float4*)&outb[((long)(n0 + row) << 8) + c4] = v;
    }
}

// ---------------------------------------------------------------------------
extern "C" void kernel_launch(void* const* d_in, const int* in_sizes, int n_in,
                              void* d_out, int out_size, void* d_ws, size_t ws_size,
                              hipStream_t stream)
{
    const float* x = (const float*)d_in[0];
    const float* m_W0  = (const float*)d_in[1];
    const float* f_W0  = (const float*)d_in[2];
    const float* m_b0  = (const float*)d_in[3];
    const float* f_b0  = (const float*)d_in[4];
    const float* m_g0  = (const float*)d_in[5];
    const float* f_g0  = (const float*)d_in[6];
    const float* m_be0 = (const float*)d_in[7];
    const float* f_be0 = (const float*)d_in[8];
    const float* m_mu0 = (const float*)d_in[9];
    const float* f_mu0 = (const float*)d_in[10];
    const float* m_var0= (const float*)d_in[11];
    const float* f_var0= (const float*)d_in[12];
    const float* m_W1  = (const float*)d_in[13];
    const float* f_W1  = (const float*)d_in[14];
    const float* m_b1  = (const float*)d_in[15];
    const float* f_b1  = (const float*)d_in[16];
    const float* m_g1  = (const float*)d_in[17];
    const float* f_g1  = (const float*)d_in[18];
    const float* m_be1 = (const float*)d_in[19];
    const float* f_be1 = (const float*)d_in[20];
    const float* m_mu1 = (const float*)d_in[21];
    const float* f_mu1 = (const float*)d_in[22];
    const float* m_var1= (const float*)d_in[23];
    const float* f_var1= (const float*)d_in[24];

    char* wsb = (char*)d_ws;
    float* fr  = (float*)wsb;                       // 32768 x 256 f32
    float* mBf = (float*)(wsb + 33554432);
    float* mS1 = mBf + 256;
    float* mT1 = mS1 + 256;
    float* fBf = mT1 + 256;
    float* fS1 = fBf + 256;
    float* fT1 = fS1 + 256;
    unsigned short* mWhi = (unsigned short*)(fT1 + 256);  // 32768 each
    unsigned short* mWlo = mWhi + 32768;
    unsigned short* fWhi = mWlo + 32768;
    unsigned short* fWlo = fWhi + 32768;

    fold_bias<<<2, 256, 0, stream>>>(
        m_W1, m_b1, m_g0, m_be0, m_mu0, m_var0, m_g1, m_be1, m_mu1, m_var1,
        f_W1, f_b1, f_g0, f_be0, f_mu0, f_var0, f_g1, f_be1, f_mu1, f_var1,
        mBf, mS1, mT1, fBf, fS1, fT1);

    fold_w<<<32, 256, 0, stream>>>(
        m_W1, m_g0, m_var0, f_W1, f_g0, f_var0,
        mWhi, mWlo, fWhi, fWlo);

    fr_kernel<<<8 * N_PTS / 32, 256, 0, stream>>>(
        x, f_W0, f_b0, (const short8*)fWhi, (const short8*)fWlo,
        fBf, fS1, fT1, fr);

    fused_kernel<<<8 * N_PTS / 16, 256, 0, stream>>>(
        x, m_W0, m_b0, (const short8*)mWhi, (const short8*)mWlo,
        mBf, mS1, mT1, fr, (float*)d_out);
}

// Round 10
// 199.521 us; speedup vs baseline: 1.2011x; 1.0253x over previous
//
#include <hip/hip_runtime.h>
#include <hip/hip_bf16.h>

#define N_PTS 4096
#define C_LIGHT 0.49965409666666664f
#define BN_EPS 1e-3f

typedef __attribute__((ext_vector_type(8))) short short8;
typedef __attribute__((ext_vector_type(4))) float f32x4;

static __device__ __forceinline__ unsigned short f2bf(float f) {
    unsigned u = __float_as_uint(f);
    u += 0x7FFFu + ((u >> 16) & 1u);
    return (unsigned short)(u >> 16);
}
static __device__ __forceinline__ float bf2f(unsigned short h) {
    return __uint_as_float(((unsigned)h) << 16);
}
// pack 2 floats -> 2 bf16 (RNE) in one u32; maps to v_cvt_pk_bf16_f32
static __device__ __forceinline__ unsigned pk2(float a, float b) {
    __hip_bfloat162 h = __float22bfloat162_rn(make_float2(a, b));
    union { __hip_bfloat162 v; unsigned u; } cv;
    cv.v = h;
    return cv.u;
}

// ---------------------------------------------------------------------------
// fold_all: 34 blocks.
//   blocks 0,1 (br = bid): Bf = b1 + t0@W1; S1; T1  for m/f branch.
//   blocks 2..33: Wf = diag(s0)@W1 split to bf16 hi/lo in B-fragment order
//     [ct(16)][ks(4)][lane(64)][j(8)]:
//     element = Wf[ks*32 + (lane>>4)*8 + j][ct*16 + (lane&15)]
// ---------------------------------------------------------------------------
__global__ __launch_bounds__(256) void fold_all(
    const float* __restrict__ mW1, const float* __restrict__ mb1,
    const float* __restrict__ mg0, const float* __restrict__ mbe0,
    const float* __restrict__ mmu0, const float* __restrict__ mvar0,
    const float* __restrict__ mg1, const float* __restrict__ mbe1,
    const float* __restrict__ mmu1, const float* __restrict__ mvar1,
    const float* __restrict__ fW1p, const float* __restrict__ fb1,
    const float* __restrict__ fg0, const float* __restrict__ fbe0,
    const float* __restrict__ fmu0, const float* __restrict__ fvar0,
    const float* __restrict__ fg1, const float* __restrict__ fbe1,
    const float* __restrict__ fmu1, const float* __restrict__ fvar1,
    float* __restrict__ mBf, float* __restrict__ mS1, float* __restrict__ mT1,
    float* __restrict__ fBf, float* __restrict__ fS1, float* __restrict__ fT1,
    unsigned short* __restrict__ mWhi, unsigned short* __restrict__ mWlo,
    unsigned short* __restrict__ fWhi, unsigned short* __restrict__ fWlo)
{
    int bid = blockIdx.x;
    int t = threadIdx.x;

    if (bid < 2) {
        int br = bid;
        const float* W1  = br ? fW1p : mW1;
        const float* b1  = br ? fb1  : mb1;
        const float* g0  = br ? fg0  : mg0;
        const float* be0 = br ? fbe0 : mbe0;
        const float* mu0 = br ? fmu0 : mmu0;
        const float* var0= br ? fvar0: mvar0;
        const float* g1  = br ? fg1  : mg1;
        const float* be1 = br ? fbe1 : mbe1;
        const float* mu1 = br ? fmu1 : mmu1;
        const float* var1= br ? fvar1: mvar1;
        float* Bf = br ? fBf : mBf;
        float* S1 = br ? fS1 : mS1;
        float* T1 = br ? fT1 : mT1;

        __shared__ float t0s[128];
        if (t < 128) {
            float s = g0[t] / sqrtf(var0[t] + BN_EPS);
            t0s[t] = be0[t] - mu0[t] * s;
        }
        __syncthreads();

        float s1 = g1[t] / sqrtf(var1[t] + BN_EPS);
        S1[t] = s1;
        T1[t] = be1[t] - mu1[t] * s1;
        float acc = b1[t];
        for (int i = 0; i < 128; ++i) acc = fmaf(t0s[i], W1[i * 256 + t], acc);
        Bf[t] = acc;
    } else {
        int wbid = bid - 2;
        int br = wbid >> 4, blk = wbid & 15;
        const float* W1  = br ? fW1p : mW1;
        const float* g0  = br ? fg0  : mg0;
        const float* var0= br ? fvar0: mvar0;
        unsigned short* Whi = br ? fWhi : mWhi;
        unsigned short* Wlo = br ? fWlo : mWlo;

        __shared__ float s0s[128];
        if (t < 128) s0s[t] = g0[t] / sqrtf(var0[t] + BN_EPS);
        __syncthreads();

        int e0 = blk * 2048 + t * 8;
        int l = (e0 >> 3) & 63, ks = (e0 >> 9) & 3, ct = e0 >> 11;
        int c = ct * 16 + (l & 15);
        int ib = ks * 32 + (l >> 4) * 8;
        unsigned short hi[8], lo[8];
#pragma unroll
        for (int j = 0; j < 8; ++j) {
            float w = s0s[ib + j] * W1[(ib + j) * 256 + c];
            hi[j] = f2bf(w);
            lo[j] = f2bf(w - bf2f(hi[j]));
        }
        *(uint4*)&Whi[e0] = *(uint4*)hi;
        *(uint4*)&Wlo[e0] = *(uint4*)lo;
    }
}

// ---------------------------------------------------------------------------
// Fully fused: FR branch (in-block, 32-row window) + H + M-branch + A-layer.
// Block: 256 thr, 16 n-positions. FR keeps fr in LDS (no HBM round-trip).
// ---------------------------------------------------------------------------
#define SM_XS    0        // 32*6*4 = 768
#define SM_B0F   768      // 512          -> 1280
#define SM_W0F   1280     // 6*136*4 = 3264 -> 4544
#define SM_B0M   4544     // 512          -> 5056
#define SM_W0M   5056     // 12*136*4 = 6528 -> 11584
#define SM_HF    11584    // 144*12*4 = 6912 -> 18496
#define SM_FRFRG 18496    // hi 2048 + lo 2048 = 4096 -> 22592
#define SM_MFRG  22592    // hi 9216 + lo 9216 = 18432 -> 41024
#define SM_OUT   22592    // overlay on MFRG: 16*260*4 = 16640
#define SM_FRL   41024    // 32*260*4 = 33280 -> 74304
#define SM_TOT   74304

__global__ __launch_bounds__(256, 2) void fused_kernel(
    const float* __restrict__ x,     // (B, N, 6)
    const float* __restrict__ mW0,   // 12x128
    const float* __restrict__ mb0,
    const float* __restrict__ fW0,   // 6x128
    const float* __restrict__ fb0,
    const short8* __restrict__ mWfHi, const short8* __restrict__ mWfLo,
    const short8* __restrict__ fWfHi, const short8* __restrict__ fWfLo,
    const float* __restrict__ mBf, const float* __restrict__ mS1,
    const float* __restrict__ mT1,
    const float* __restrict__ fBf, const float* __restrict__ fS1,
    const float* __restrict__ fT1,
    float* __restrict__ out)         // (B, N, 256)
{
    __shared__ __attribute__((aligned(16))) char smem[SM_TOT];
    float* xs   = (float*)(smem + SM_XS);     // rows n0-8 .. n0+23
    float* b0f  = (float*)(smem + SM_B0F);
    float* w0f  = (float*)(smem + SM_W0F);
    float* b0m  = (float*)(smem + SM_B0M);
    float* w0m  = (float*)(smem + SM_W0M);
    float* hfp  = (float*)(smem + SM_HF);
    float* frL  = (float*)(smem + SM_FRL);
    float* oL   = (float*)(smem + SM_OUT);

    int t = threadIdx.x;
    int bn = blockIdx.x;
    int b  = bn >> 8;
    int n0 = (bn & 255) << 4;
    const float* xb = x + (long)b * N_PTS * 6;

    // ---- stage x window [n0-8, n0+23] and all weights ----
    if (t < 192) {                       // 32 rows x 6 cols
        int rr = t / 6, cc = t % 6;
        int n = n0 - 8 + rr;
        xs[rr * 6 + cc] = (n >= 0 && n < N_PTS) ? xb[n * 6 + cc] : 0.f;
    }
    for (int i = t; i < 768; i += 256)  w0f[(i >> 7) * 136 + (i & 127)] = fW0[i];
    for (int i = t; i < 1536; i += 256) w0m[(i >> 7) * 136 + (i & 127)] = mW0[i];
    if (t < 128) { b0f[t] = fb0[t]; b0m[t] = mb0[t]; }
    __syncthreads();

    // ---- H features (needs xs only): row = kt*16 + nl ----
    if (t < 144) {
        int kt = t >> 4, nl = t & 15;
        const float* self = &xs[(nl + 8) * 6];
        const float* nb   = &xs[(nl + kt + 4) * 6];
        int nbn = n0 + nl + kt - 4;
        float msk = (nbn >= 0 && nbn < N_PTS) ? 1.f : 0.f;
        float dt = (nb[0] - self[0]) * msk;
        float dx = (nb[3] - self[3]) * msk;
        float dy = (nb[4] - self[4]) * msk;
        float dz = (nb[5] - self[5]) * msk;
        float eu2 = dx * dx + dy * dy + dz * dz;
        float* h = &hfp[t * 12];
        h[0]  = nb[0];
        h[1]  = nb[3];
        h[2]  = nb[4];
        h[3]  = nb[5];
        h[4]  = nb[1];
        h[5]  = nb[2];
        h[6]  = dt;
        h[7]  = dx;
        h[8]  = dy;
        h[9]  = dz;
        h[10] = sqrtf(eu2);
        float cdt = C_LIGHT * dt;
        h[11] = cdt * cdt - eu2;
    }

    int lane = t & 63, wv = t >> 6;
    int laneN = lane & 15, laneH = lane >> 4;
    int cg = t & 7;
    int rowh = t >> 3;                   // 0..31

    int colc[4];
#pragma unroll
    for (int c = 0; c < 4; ++c) colc[c] = (wv * 4 + c) * 16 + laneN;

    // =======================================================================
    // FR phase: fr rows [n0-8, n0+23] -> frL (f32, zero for OOB rows)
    // =======================================================================
    {
        unsigned short* Fhi = (unsigned short*)(smem + SM_FRFRG);
        unsigned short* Flo = Fhi + 2048;

        f32x4 accF[2][4];
#pragma unroll
        for (int mt = 0; mt < 2; ++mt)
#pragma unroll
            for (int c = 0; c < 4; ++c) {
                float bv = fBf[colc[c]];
                f32x4 z = {bv, bv, bv, bv};
                accF[mt][c] = z;
            }

        for (int ks = 0; ks < 4; ++ks) {
            if (ks) __syncthreads();         // frag buffer reuse
            {   // hidden slice: one row-group per thread
                int k0 = ks * 32 + cg * 4;
                float a0 = b0f[k0], a1 = b0f[k0+1], a2 = b0f[k0+2], a3 = b0f[k0+3];
#pragma unroll
                for (int i = 0; i < 6; ++i) {
                    float hv = xs[rowh * 6 + i];
                    a0 = fmaf(hv, w0f[i * 136 + k0],     a0);
                    a1 = fmaf(hv, w0f[i * 136 + k0 + 1], a1);
                    a2 = fmaf(hv, w0f[i * 136 + k0 + 2], a2);
                    a3 = fmaf(hv, w0f[i * 136 + k0 + 3], a3);
                }
                a0 = fmaxf(a0, 0.f); a1 = fmaxf(a1, 0.f);
                a2 = fmaxf(a2, 0.f); a3 = fmaxf(a3, 0.f);
                unsigned hi01 = pk2(a0, a1), hi23 = pk2(a2, a3);
                float q0 = __uint_as_float(hi01 << 16);
                float q1 = __uint_as_float(hi01 & 0xffff0000u);
                float q2 = __uint_as_float(hi23 << 16);
                float q3 = __uint_as_float(hi23 & 0xffff0000u);
                unsigned lo01 = pk2(a0 - q0, a1 - q1), lo23 = pk2(a2 - q2, a3 - q3);
                int mt = rowh >> 4, nl2 = rowh & 15;
                int base = (mt * 64 + (cg >> 1) * 16 + nl2) * 8 + (cg & 1) * 4;
                *(uint2*)&Fhi[base] = make_uint2(hi01, hi23);
                *(uint2*)&Flo[base] = make_uint2(lo01, lo23);
            }
            __syncthreads();
            short8 Bhi[4], Blo[4];
#pragma unroll
            for (int c = 0; c < 4; ++c) {
                int fo = ((wv * 4 + c) * 4 + ks) * 64 + lane;
                Bhi[c] = fWfHi[fo];
                Blo[c] = fWfLo[fo];
            }
#pragma unroll
            for (int mt = 0; mt < 2; ++mt) {
                short8 Ahi = *(const short8*)&Fhi[(mt * 64 + lane) * 8];
                short8 Alo = *(const short8*)&Flo[(mt * 64 + lane) * 8];
#pragma unroll
                for (int c = 0; c < 4; ++c) {
                    f32x4 a = accF[mt][c];
                    a = __builtin_amdgcn_mfma_f32_16x16x32_bf16(Alo, Bhi[c], a, 0, 0, 0);
                    a = __builtin_amdgcn_mfma_f32_16x16x32_bf16(Ahi, Blo[c], a, 0, 0, 0);
                    a = __builtin_amdgcn_mfma_f32_16x16x32_bf16(Ahi, Bhi[c], a, 0, 0, 0);
                    accF[mt][c] = a;
                }
            }
        }

        // FR epilogue -> frL (zero OOB rows)
#pragma unroll
        for (int c = 0; c < 4; ++c) {
            float s1 = fS1[colc[c]], t1 = fT1[colc[c]];
#pragma unroll
            for (int mt = 0; mt < 2; ++mt)
#pragma unroll
                for (int r = 0; r < 4; ++r) {
                    int rl = mt * 16 + laneH * 4 + r;
                    int nn = n0 - 8 + rl;
                    float y = fmaf(fmaxf(accF[mt][c][r], 0.f), s1, t1);
                    frL[rl * 260 + colc[c]] =
                        (nn >= 0 && nn < N_PTS) ? y : 0.f;
                }
        }
    }
    __syncthreads();

    // =======================================================================
    // M phase: 144 rows (9 k-tiles x 16 n), single-buffered A-frags
    // =======================================================================
    float s1v[4], t1v[4];
#pragma unroll
    for (int c = 0; c < 4; ++c) { s1v[c] = mS1[colc[c]]; t1v[c] = mT1[colc[c]]; }

    f32x4 acc[9][4];
#pragma unroll
    for (int kt = 0; kt < 9; ++kt)
#pragma unroll
        for (int c = 0; c < 4; ++c) {
            float bv = mBf[colc[c]];
            f32x4 z = {bv, bv, bv, bv};
            acc[kt][c] = z;
        }

    unsigned short* Hhi = (unsigned short*)(smem + SM_MFRG);
    unsigned short* Hlo = Hhi + 4608;

    for (int ks = 0; ks < 4; ++ks) {
        if (ks) __syncthreads();             // protect single frag buffer
        {
            int k0 = ks * 32 + cg * 4;
            float4 wreg[12];
#pragma unroll
            for (int i = 0; i < 12; ++i) wreg[i] = *(const float4*)&w0m[i * 136 + k0];
            float4 bq = *(const float4*)&b0m[k0];
            for (int idx = t; idx < 1152; idx += 256) {
                int row = idx >> 3;
                float a0 = bq.x, a1 = bq.y, a2 = bq.z, a3 = bq.w;
#pragma unroll
                for (int i = 0; i < 12; ++i) {
                    float hv = hfp[row * 12 + i];
                    a0 = fmaf(hv, wreg[i].x, a0);
                    a1 = fmaf(hv, wreg[i].y, a1);
                    a2 = fmaf(hv, wreg[i].z, a2);
                    a3 = fmaf(hv, wreg[i].w, a3);
                }
                a0 = fmaxf(a0, 0.f); a1 = fmaxf(a1, 0.f);
                a2 = fmaxf(a2, 0.f); a3 = fmaxf(a3, 0.f);
                unsigned hi01 = pk2(a0, a1), hi23 = pk2(a2, a3);
                float q0 = __uint_as_float(hi01 << 16);
                float q1 = __uint_as_float(hi01 & 0xffff0000u);
                float q2 = __uint_as_float(hi23 << 16);
                float q3 = __uint_as_float(hi23 & 0xffff0000u);
                unsigned lo01 = pk2(a0 - q0, a1 - q1), lo23 = pk2(a2 - q2, a3 - q3);
                int kt = row >> 4, nl = row & 15;
                int base = (kt * 64 + (cg >> 1) * 16 + nl) * 8 + (cg & 1) * 4;
                *(uint2*)&Hhi[base] = make_uint2(hi01, hi23);
                *(uint2*)&Hlo[base] = make_uint2(lo01, lo23);
            }
        }
        __syncthreads();
        short8 Bhi[4], Blo[4];
#pragma unroll
        for (int c = 0; c < 4; ++c) {
            int fo = ((wv * 4 + c) * 4 + ks) * 64 + lane;
            Bhi[c] = mWfHi[fo];
            Blo[c] = mWfLo[fo];
        }
#pragma unroll
        for (int kt = 0; kt < 9; ++kt) {
            short8 Ahi = *(const short8*)&Hhi[(kt * 64 + lane) * 8];
            short8 Alo = *(const short8*)&Hlo[(kt * 64 + lane) * 8];
#pragma unroll
            for (int c = 0; c < 4; ++c) {
                f32x4 a = acc[kt][c];
                a = __builtin_amdgcn_mfma_f32_16x16x32_bf16(Alo, Bhi[c], a, 0, 0, 0);
                a = __builtin_amdgcn_mfma_f32_16x16x32_bf16(Ahi, Blo[c], a, 0, 0, 0);
                a = __builtin_amdgcn_mfma_f32_16x16x32_bf16(Ahi, Bhi[c], a, 0, 0, 0);
                acc[kt][c] = a;
            }
        }
    }
    __syncthreads();    // M frag LDS dead -> oL overlay safe

    // =======================================================================
    // A-layer epilogue: m = relu(acc)*S1+T1; T = m * frL[nl+kt+4]; max over kt
    // =======================================================================
#pragma unroll
    for (int c = 0; c < 4; ++c) {
        float fv[12];
        int fb = (laneH * 4 + 4) * 260 + colc[c];
#pragma unroll
        for (int j = 0; j < 12; ++j) fv[j] = frL[fb + j * 260];
#pragma unroll
        for (int r = 0; r < 4; ++r) {
            float best;
#pragma unroll
            for (int kt = 0; kt < 9; ++kt) {
                float m = fmaf(fmaxf(acc[kt][c][r], 0.f), s1v[c], t1v[c]);
                float T = m * fv[r + kt];
                best = (kt == 0) ? T : fmaxf(best, T);
            }
            oL[(laneH * 4 + r) * 260 + colc[c]] = best;
        }
    }
    __syncthreads();

    float* outb = out + ((long)b << 20);
    for (int i = t; i < 1024; i += 256) {
        int row = i >> 6, c4 = (i & 63) << 2;
        float4 v = *(const float4*)&oL[row * 260 + c4];
        *(float4*)&outb[((long)(n0 + row) << 8) + c4] = v;
    }
}

// ---------------------------------------------------------------------------
extern "C" void kernel_launch(void* const* d_in, const int* in_sizes, int n_in,
                              void* d_out, int out_size, void* d_ws, size_t ws_size,
                              hipStream_t stream)
{
    const float* x = (const float*)d_in[0];
    const float* m_W0  = (const float*)d_in[1];
    const float* f_W0  = (const float*)d_in[2];
    const float* m_b0  = (const float*)d_in[3];
    const float* f_b0  = (const float*)d_in[4];
    const float* m_g0  = (const float*)d_in[5];
    const float* f_g0  = (const float*)d_in[6];
    const float* m_be0 = (const float*)d_in[7];
    const float* f_be0 = (const float*)d_in[8];
    const float* m_mu0 = (const float*)d_in[9];
    const float* f_mu0 = (const float*)d_in[10];
    const float* m_var0= (const float*)d_in[11];
    const float* f_var0= (const float*)d_in[12];
    const float* m_W1  = (const float*)d_in[13];
    const float* f_W1  = (const float*)d_in[14];
    const float* m_b1  = (const float*)d_in[15];
    const float* f_b1  = (const float*)d_in[16];
    const float* m_g1  = (const float*)d_in[17];
    const float* f_g1  = (const float*)d_in[18];
    const float* m_be1 = (const float*)d_in[19];
    const float* f_be1 = (const float*)d_in[20];
    const float* m_mu1 = (const float*)d_in[21];
    const float* f_mu1 = (const float*)d_in[22];
    const float* m_var1= (const float*)d_in[23];
    const float* f_var1= (const float*)d_in[24];

    float* ws  = (float*)d_ws;
    float* mBf = ws;                 // 6 x 256 f32 scale/shift blocks
    float* mS1 = mBf + 256;
    float* mT1 = mS1 + 256;
    float* fBf = mT1 + 256;
    float* fS1 = fBf + 256;
    float* fT1 = fS1 + 256;
    unsigned short* mWhi = (unsigned short*)(fT1 + 256);  // 32768 u16 each
    unsigned short* mWlo = mWhi + 32768;
    unsigned short* fWhi = mWlo + 32768;
    unsigned short* fWlo = fWhi + 32768;

    fold_all<<<34, 256, 0, stream>>>(
        m_W1, m_b1, m_g0, m_be0, m_mu0, m_var0, m_g1, m_be1, m_mu1, m_var1,
        f_W1, f_b1, f_g0, f_be0, f_mu0, f_var0, f_g1, f_be1, f_mu1, f_var1,
        mBf, mS1, mT1, fBf, fS1, fT1,
        mWhi, mWlo, fWhi, fWlo);

    fused_kernel<<<8 * N_PTS / 16, 256, 0, stream>>>(
        x, m_W0, m_b0, f_W0, f_b0,
        (const short8*)mWhi, (const short8*)mWlo,
        (const short8*)fWhi, (const short8*)fWlo,
        mBf, mS1, mT1, fBf, fS1, fT1,
        (float*)d_out);
}